// Round 1
// baseline (1575.024 us; speedup 1.0000x reference)
//
#include <hip/hip_runtime.h>
#include <stdint.h>
#include <stddef.h>

// Problem constants (from reference setup_inputs)
#define NSLOT 8
#define OUTF  4096
#define INF   4096
#define MDIM  16384   // B*S = 8*2048
#define KDIM  4096
#define NDIM  4096
#define NTILE (KDIM / 64)

typedef __bf16 bf16x8 __attribute__((ext_vector_type(8)));
typedef float f32x4 __attribute__((ext_vector_type(4)));
typedef unsigned short u16x8 __attribute__((ext_vector_type(8)));

// round-to-nearest-even f32 -> bf16 bits (finite inputs only)
__device__ __forceinline__ unsigned short f2bf(float f) {
  unsigned u = __builtin_bit_cast(unsigned, f);
  u += 0x7fffu + ((u >> 16) & 1u);
  return (unsigned short)(u >> 16);
}

// ---- kernel 1: scalar coefficients ----
__global__ void coeff_kernel(const float* __restrict__ scale,
                             const float* __restrict__ wscale,
                             const int* __restrict__ wzp,
                             const float* __restrict__ bscale,
                             const int* __restrict__ bzp,
                             float* __restrict__ co) {
  if (threadIdx.x == 0) {
    float c = 0.f, cb = 0.f;
    for (int i = 0; i < NSLOT; ++i) {
      co[i]     = scale[i] * wscale[i];
      co[9 + i] = scale[i] * bscale[i];
      c  += scale[i] * (float)wzp[i];
      cb += scale[i] * (float)bzp[i];
    }
    co[8]  = c;
    co[17] = cb;
  }
}

// ---- kernel 2: W' = weight + sum_i a_i*wq_i + c, stored as bf16 bits ----
__global__ __launch_bounds__(256) void dequant_w(const float* __restrict__ weight,
                                                 const int* __restrict__ wq,
                                                 const float* __restrict__ co,
                                                 unsigned short* __restrict__ wd) {
  const size_t base = ((size_t)blockIdx.x * 256 + threadIdx.x) * 8;
  const float c = co[8];
  float4 w0 = *(const float4*)(weight + base);
  float4 w1 = *(const float4*)(weight + base + 4);
  float acc[8] = {w0.x + c, w0.y + c, w0.z + c, w0.w + c,
                  w1.x + c, w1.y + c, w1.z + c, w1.w + c};
#pragma unroll
  for (int i = 0; i < NSLOT; ++i) {
    const float a = co[i];
    const int* q = wq + (size_t)i * ((size_t)OUTF * INF) + base;
    int4 q0 = *(const int4*)q;
    int4 q1 = *(const int4*)(q + 4);
    acc[0] += a * (float)q0.x; acc[1] += a * (float)q0.y;
    acc[2] += a * (float)q0.z; acc[3] += a * (float)q0.w;
    acc[4] += a * (float)q1.x; acc[5] += a * (float)q1.y;
    acc[6] += a * (float)q1.z; acc[7] += a * (float)q1.w;
  }
  u16x8 p;
#pragma unroll
  for (int e = 0; e < 8; ++e) p[e] = f2bf(acc[e]);
  *(u16x8*)(wd + base) = p;
}

// ---- kernel 3: x f32 -> bf16 ----
__global__ __launch_bounds__(256) void xconv(const float* __restrict__ x,
                                             unsigned short* __restrict__ xb) {
  const size_t base = ((size_t)blockIdx.x * 256 + threadIdx.x) * 8;
  float4 v0 = *(const float4*)(x + base);
  float4 v1 = *(const float4*)(x + base + 4);
  u16x8 p;
  p[0] = f2bf(v0.x); p[1] = f2bf(v0.y); p[2] = f2bf(v0.z); p[3] = f2bf(v0.w);
  p[4] = f2bf(v1.x); p[5] = f2bf(v1.y); p[6] = f2bf(v1.z); p[7] = f2bf(v1.w);
  *(u16x8*)(xb + base) = p;
}

// ---- kernel 4: b' = bias + sum_i ab_i*bq_i + cb ----
__global__ __launch_bounds__(256) void bias_fuse(const float* __restrict__ bias,
                                                 const int* __restrict__ bq,
                                                 const float* __restrict__ co,
                                                 float* __restrict__ bv) {
  const int o = blockIdx.x * 256 + threadIdx.x;
  float acc = bias[o] + co[17];
#pragma unroll
  for (int i = 0; i < NSLOT; ++i)
    acc += co[9 + i] * (float)bq[i * OUTF + o];
  bv[o] = acc;
}

// ---- kernel 5: bf16 GEMM, C = A(16384x4096) * W'(4096x4096)^T + b' ----
// 256x256 tile, BK=64, 8 waves (2Mx4N), 128 KiB double-buffered LDS.
// T1 XCD-chunked block swizzle; T2 st-XOR LDS swizzle (byte ^= (row&7)<<4),
// applied as pre-swizzled GLOBAL source + swizzled ds_read (linear LDS dest
// for global_load_lds, rule 21); T3/T4 4-phase interleave per K-tile with
// loads in flight across barriers, single per-tile vmcnt(0); T5 setprio.
__global__ __launch_bounds__(512, 2) void gemm256(const unsigned short* __restrict__ A,
                                                  const unsigned short* __restrict__ Bw,
                                                  const float* __restrict__ bv,
                                                  float* __restrict__ C) {
  __shared__ __attribute__((aligned(16))) unsigned short sA[2 * 16384];
  __shared__ __attribute__((aligned(16))) unsigned short sB[2 * 16384];

  const int tid  = threadIdx.x;
  const int lane = tid & 63;
  const int wave = tid >> 6;           // 0..7
  const int wm   = (wave >> 2) * 128;  // 0 or 128
  const int wn   = (wave & 3) * 64;    // 0,64,128,192

  // T1: XCD-chunked bijective block swizzle (1024 = 8 * 128).
  // Within an XCD chunk: m-row-major, so ~32 concurrent blocks/XCD share 2
  // A-panels (4 MB, fits the 4 MiB per-XCD L2).
  const int bid = blockIdx.x;
  const int wg  = ((bid & 7) << 7) | (bid >> 3);
  const int m0  = (wg >> 4) << 8;      // 0..63 * 256
  const int n0  = (wg & 15) << 8;      // 0..15 * 256

  // fragment addressing (mfma_f32_16x16x32_bf16): row = lane&15, k-chunk = lane>>4
  const int fr   = lane & 15;
  const int q    = lane >> 4;
  const int fx8  = (fr & 7) << 3;           // swizzle term (elems)
  const int qa0  = (q << 3) ^ fx8;          // kk=0: swizzled k-offset within row
  const int qa1  = ((4 + q) << 3) ^ fx8;    // kk=1
  const int rowA = (wm + fr) << 6;          // row * 64 elems
  const int rowB = (wn + fr) << 6;

  // staging addressing: thread t covers rows j*64 + (t>>3); global col chunk is
  // pre-swizzled by (row&7) so linear LDS dest yields swizzled layout.
  const int srow = tid >> 3;                               // 0..63
  const int scol = ((tid & 7) ^ (srow & 7)) << 3;          // elems within BK=64
  const unsigned short* gA = A  + (size_t)(m0 + srow) * KDIM + scol;
  const unsigned short* gB = Bw + (size_t)(n0 + srow) * KDIM + scol;

  f32x4 acc[8][4] = {};

#define STAGE_A(kt, b)                                                          \
  {                                                                             \
    _Pragma("unroll")                                                           \
    for (int j = 0; j < 4; ++j)                                                 \
      __builtin_amdgcn_global_load_lds(                                         \
          (const __attribute__((address_space(1))) void*)(gA + (size_t)(kt) * 64 + (size_t)j * 64 * KDIM), \
          (__attribute__((address_space(3))) void*)(sA + (b) * 16384 + j * 4096 + tid * 8), 16, 0, 0); \
  }
#define STAGE_B(kt, b)                                                          \
  {                                                                             \
    _Pragma("unroll")                                                           \
    for (int j = 0; j < 4; ++j)                                                 \
      __builtin_amdgcn_global_load_lds(                                         \
          (const __attribute__((address_space(1))) void*)(gB + (size_t)(kt) * 64 + (size_t)j * 64 * KDIM), \
          (__attribute__((address_space(3))) void*)(sB + (b) * 16384 + j * 4096 + tid * 8), 16, 0, 0); \
  }

#define MFMA4(ii, AF, BF)                                                       \
  {                                                                             \
    _Pragma("unroll")                                                           \
    for (int j = 0; j < 4; ++j)                                                 \
      acc[ii][j] = __builtin_amdgcn_mfma_f32_16x16x32_bf16(AF, BF[j], acc[ii][j], 0, 0, 0); \
  }

  // prologue: stage tile 0 into buffer 0, wait, barrier
  STAGE_A(0, 0);
  STAGE_B(0, 0);
  asm volatile("s_waitcnt vmcnt(0)" ::: "memory");
  __builtin_amdgcn_sched_barrier(0);
  __builtin_amdgcn_s_barrier();

  for (int t = 0; t < NTILE; ++t) {
    const int cur = t & 1;
    const unsigned short* bufA = sA + cur * 16384;
    const unsigned short* bufB = sB + cur * 16384;
    bf16x8 bf0[4], bf1[4];

    // ---------------- phase 1: B all + A frags 0,1 ; prefetch A(t+1) ----
    {
      bf16x8 x00 = *(const bf16x8*)(bufA + rowA + 0 * 1024 + qa0);
      bf16x8 x01 = *(const bf16x8*)(bufA + rowA + 0 * 1024 + qa1);
      bf16x8 x10 = *(const bf16x8*)(bufA + rowA + 1 * 1024 + qa0);
      bf16x8 x11 = *(const bf16x8*)(bufA + rowA + 1 * 1024 + qa1);
#pragma unroll
      for (int j = 0; j < 4; ++j) {
        bf0[j] = *(const bf16x8*)(bufB + rowB + j * 1024 + qa0);
        bf1[j] = *(const bf16x8*)(bufB + rowB + j * 1024 + qa1);
      }
      if (t + 1 < NTILE) STAGE_A(t + 1, cur ^ 1);
      __builtin_amdgcn_s_barrier();
      __builtin_amdgcn_sched_barrier(0);
      __builtin_amdgcn_s_setprio(1);
      MFMA4(0, x00, bf0); MFMA4(1, x10, bf0);
      MFMA4(0, x01, bf1); MFMA4(1, x11, bf1);
      __builtin_amdgcn_s_setprio(0);
      __builtin_amdgcn_s_barrier();
    }
    // ---------------- phase 2: A frags 2,3 ; prefetch B(t+1) ----
    {
      bf16x8 x00 = *(const bf16x8*)(bufA + rowA + 2 * 1024 + qa0);
      bf16x8 x01 = *(const bf16x8*)(bufA + rowA + 2 * 1024 + qa1);
      bf16x8 x10 = *(const bf16x8*)(bufA + rowA + 3 * 1024 + qa0);
      bf16x8 x11 = *(const bf16x8*)(bufA + rowA + 3 * 1024 + qa1);
      if (t + 1 < NTILE) STAGE_B(t + 1, cur ^ 1);
      __builtin_amdgcn_s_barrier();
      __builtin_amdgcn_sched_barrier(0);
      __builtin_amdgcn_s_setprio(1);
      MFMA4(2, x00, bf0); MFMA4(3, x10, bf0);
      MFMA4(2, x01, bf1); MFMA4(3, x11, bf1);
      __builtin_amdgcn_s_setprio(0);
      __builtin_amdgcn_s_barrier();
    }
    // ---------------- phase 3: A frags 4,5 ----
    {
      bf16x8 x00 = *(const bf16x8*)(bufA + rowA + 4 * 1024 + qa0);
      bf16x8 x01 = *(const bf16x8*)(bufA + rowA + 4 * 1024 + qa1);
      bf16x8 x10 = *(const bf16x8*)(bufA + rowA + 5 * 1024 + qa0);
      bf16x8 x11 = *(const bf16x8*)(bufA + rowA + 5 * 1024 + qa1);
      __builtin_amdgcn_s_barrier();
      __builtin_amdgcn_sched_barrier(0);
      __builtin_amdgcn_s_setprio(1);
      MFMA4(4, x00, bf0); MFMA4(5, x10, bf0);
      MFMA4(4, x01, bf1); MFMA4(5, x11, bf1);
      __builtin_amdgcn_s_setprio(0);
      __builtin_amdgcn_s_barrier();
    }
    // ---------------- phase 4: A frags 6,7 ; tile-boundary vmcnt ----
    {
      bf16x8 x00 = *(const bf16x8*)(bufA + rowA + 6 * 1024 + qa0);
      bf16x8 x01 = *(const bf16x8*)(bufA + rowA + 6 * 1024 + qa1);
      bf16x8 x10 = *(const bf16x8*)(bufA + rowA + 7 * 1024 + qa0);
      bf16x8 x11 = *(const bf16x8*)(bufA + rowA + 7 * 1024 + qa1);
      __builtin_amdgcn_s_barrier();
      __builtin_amdgcn_sched_barrier(0);
      __builtin_amdgcn_s_setprio(1);
      MFMA4(6, x00, bf0); MFMA4(7, x10, bf0);
      MFMA4(6, x01, bf1); MFMA4(7, x11, bf1);
      __builtin_amdgcn_s_setprio(0);
      // all 8 prefetch loads for tile t+1 must have landed before any wave
      // reads buf[cur^1] after the next barrier
      asm volatile("s_waitcnt vmcnt(0)" ::: "memory");
      __builtin_amdgcn_sched_barrier(0);
      __builtin_amdgcn_s_barrier();
    }
  }

  // epilogue: C/D layout col = lane&15, row = (lane>>4)*4 + reg
  const int r0 = m0 + wm + ((lane >> 4) << 2);
  const int c0 = n0 + wn + (lane & 15);
#pragma unroll
  for (int j = 0; j < 4; ++j) {
    const int col = c0 + j * 16;
    const float bb = bv[col];
#pragma unroll
    for (int i = 0; i < 8; ++i) {
      const int row = r0 + i * 16;
#pragma unroll
      for (int r = 0; r < 4; ++r)
        C[(size_t)(row + r) * NDIM + col] = acc[i][j][r] + bb;
    }
  }
#undef STAGE_A
#undef STAGE_B
#undef MFMA4
}

extern "C" void kernel_launch(void* const* d_in, const int* in_sizes, int n_in,
                              void* d_out, int out_size, void* d_ws, size_t ws_size,
                              hipStream_t stream) {
  const float* x      = (const float*)d_in[0];
  const float* weight = (const float*)d_in[1];
  const float* bias   = (const float*)d_in[2];
  const float* scale  = (const float*)d_in[3];
  const int*   wq     = (const int*)d_in[4];
  const float* wscale = (const float*)d_in[5];
  const int*   wzp    = (const int*)d_in[6];
  const int*   bq     = (const int*)d_in[7];
  const float* bscale = (const float*)d_in[8];
  const int*   bzp    = (const int*)d_in[9];
  float* out = (float*)d_out;

  // workspace layout
  char* ws = (char*)d_ws;
  unsigned short* wd = (unsigned short*)(ws);                              // 32 MB  bf16 W'
  unsigned short* xb = (unsigned short*)(ws + 33554432);                   // 128 MB bf16 x
  float* bv = (float*)(ws + 33554432 + 134217728);                         // 16 KB  b'
  float* co = (float*)(ws + 33554432 + 134217728 + 16384);                 // coeffs

  coeff_kernel<<<1, 64, 0, stream>>>(scale, wscale, wzp, bscale, bzp, co);
  dequant_w<<<(OUTF * (size_t)INF) / 8 / 256, 256, 0, stream>>>(weight, wq, co, wd);
  xconv<<<((size_t)MDIM * KDIM) / 8 / 256, 256, 0, stream>>>(x, xb);
  bias_fuse<<<OUTF / 256, 256, 0, stream>>>(bias, bq, co, bv);
  gemm256<<<dim3((MDIM / 256) * (NDIM / 256)), 512, 0, stream>>>(xb, wd, bv, out);
}

// Round 2
// 1556.252 us; speedup vs baseline: 1.0121x; 1.0121x over previous
//
#include <hip/hip_runtime.h>
#include <stdint.h>
#include <stddef.h>

// Problem constants (from reference setup_inputs)
#define NSLOT 8
#define OUTF  4096
#define INF   4096
#define MDIM  16384   // B*S = 8*2048
#define KDIM  4096
#define NDIM  4096
#define NTILE (KDIM / 64)

typedef __bf16 bf16x8 __attribute__((ext_vector_type(8)));
typedef float f32x4 __attribute__((ext_vector_type(4)));
typedef unsigned short u16x8 __attribute__((ext_vector_type(8)));

// round-to-nearest-even f32 -> bf16 bits (finite inputs only)
__device__ __forceinline__ unsigned short f2bf(float f) {
  unsigned u = __builtin_bit_cast(unsigned, f);
  u += 0x7fffu + ((u >> 16) & 1u);
  return (unsigned short)(u >> 16);
}

// ---- kernel 1: scalar coefficients ----
__global__ void coeff_kernel(const float* __restrict__ scale,
                             const float* __restrict__ wscale,
                             const int* __restrict__ wzp,
                             const float* __restrict__ bscale,
                             const int* __restrict__ bzp,
                             float* __restrict__ co) {
  if (threadIdx.x == 0) {
    float c = 0.f, cb = 0.f;
    for (int i = 0; i < NSLOT; ++i) {
      co[i]     = scale[i] * wscale[i];
      co[9 + i] = scale[i] * bscale[i];
      c  += scale[i] * (float)wzp[i];
      cb += scale[i] * (float)bzp[i];
    }
    co[8]  = c;
    co[17] = cb;
  }
}

// ---- kernel 2 (fused prep): dequant_w | xconv | bias_fuse by block range ----
// blocks [0, 8192)        : W' = weight + sum_i a_i*wq_i + c  -> bf16 wd
// blocks [8192, 40960)    : x f32 -> bf16 xb
// blocks [40960, 40976)   : b' = bias + sum_i ab_i*bq_i + cb
// Fusing overlaps the independent HBM streams and cuts launch overhead.
__global__ __launch_bounds__(256) void prep(const float* __restrict__ weight,
                                            const int* __restrict__ wq,
                                            const float* __restrict__ co,
                                            unsigned short* __restrict__ wd,
                                            const float* __restrict__ x,
                                            unsigned short* __restrict__ xb,
                                            const float* __restrict__ bias,
                                            const int* __restrict__ bq,
                                            float* __restrict__ bv) {
  const int b = blockIdx.x;
  if (b < 8192) {
    const size_t base = ((size_t)b * 256 + threadIdx.x) * 8;
    const float c = co[8];
    float4 w0 = *(const float4*)(weight + base);
    float4 w1 = *(const float4*)(weight + base + 4);
    float acc[8] = {w0.x + c, w0.y + c, w0.z + c, w0.w + c,
                    w1.x + c, w1.y + c, w1.z + c, w1.w + c};
#pragma unroll
    for (int i = 0; i < NSLOT; ++i) {
      const float a = co[i];
      const int* q = wq + (size_t)i * ((size_t)OUTF * INF) + base;
      int4 q0 = *(const int4*)q;
      int4 q1 = *(const int4*)(q + 4);
      acc[0] += a * (float)q0.x; acc[1] += a * (float)q0.y;
      acc[2] += a * (float)q0.z; acc[3] += a * (float)q0.w;
      acc[4] += a * (float)q1.x; acc[5] += a * (float)q1.y;
      acc[6] += a * (float)q1.z; acc[7] += a * (float)q1.w;
    }
    u16x8 p;
#pragma unroll
    for (int e = 0; e < 8; ++e) p[e] = f2bf(acc[e]);
    *(u16x8*)(wd + base) = p;
  } else if (b < 8192 + 32768) {
    const size_t base = ((size_t)(b - 8192) * 256 + threadIdx.x) * 8;
    float4 v0 = *(const float4*)(x + base);
    float4 v1 = *(const float4*)(x + base + 4);
    u16x8 p;
    p[0] = f2bf(v0.x); p[1] = f2bf(v0.y); p[2] = f2bf(v0.z); p[3] = f2bf(v0.w);
    p[4] = f2bf(v1.x); p[5] = f2bf(v1.y); p[6] = f2bf(v1.z); p[7] = f2bf(v1.w);
    *(u16x8*)(xb + base) = p;
  } else {
    const int o = (b - 40960) * 256 + threadIdx.x;
    float acc = bias[o] + co[17];
#pragma unroll
    for (int i = 0; i < NSLOT; ++i)
      acc += co[9 + i] * (float)bq[i * OUTF + o];
    bv[o] = acc;
  }
}

// ---- kernel 3: bf16 GEMM, C = A(16384x4096) * W'(4096x4096)^T + b' ----
// 256x256 tile, BK=64, 8 waves (2Mx4N), 128 KiB double-buffered LDS.
// ONE barrier per phase + register read-ahead-by-one: section p =
//   [stage-issue ; MFMA(p) on regs read in section p-1 ; ds_read regs for p+1 ;
//    barrier]  -- compiler emits counted lgkmcnt, so LDS reads (~1536 cyc/tile
// per CU) hide under MFMA (~2483 cyc/tile). Round-1's 2-barrier +
// sched_barrier(0) structure serialized these pipes (MfmaUtil 35%).
// Sync ledger:
//  - stage(t+1) issued S0 (A) / S1 (B) into buf cur^1; every wave vmcnt(0) at
//    end of S2 (>=1.5 sections after issue, nearly landed), THEN barrier ->
//    cross-buffer reads (S3's A-pair0, next-S0's B) are >=1 barrier after every
//    wave's vmcnt. sched_barrier(0) after S2's barrier pins the one unsafe hoist.
//  - write-after-read: buf cur^1's old data last read at S2(t-1); stage issue
//    at S0(t) is >=2 barriers later (skew <= 1 section).
__global__ __launch_bounds__(512, 2) void gemm256(const unsigned short* __restrict__ A,
                                                  const unsigned short* __restrict__ Bw,
                                                  const float* __restrict__ bv,
                                                  float* __restrict__ C) {
  __shared__ __attribute__((aligned(16))) unsigned short sA[2 * 16384];
  __shared__ __attribute__((aligned(16))) unsigned short sB[2 * 16384];

  const int tid  = threadIdx.x;
  const int lane = tid & 63;
  const int wave = tid >> 6;           // 0..7
  const int wm   = (wave >> 2) * 128;  // 0 or 128
  const int wn   = (wave & 3) * 64;    // 0,64,128,192

  // T1: XCD-chunked bijective block swizzle (1024 = 8 * 128).
  const int bid = blockIdx.x;
  const int wg  = ((bid & 7) << 7) | (bid >> 3);
  const int m0  = (wg >> 4) << 8;      // 0..63 * 256
  const int n0  = (wg & 15) << 8;      // 0..15 * 256

  // fragment addressing (mfma_f32_16x16x32_bf16): row = lane&15, k-chunk = lane>>4
  const int fr   = lane & 15;
  const int q    = lane >> 4;
  const int fx8  = (fr & 7) << 3;           // T2 swizzle term (elems)
  const int qa0  = (q << 3) ^ fx8;          // kk=0: swizzled k-offset within row
  const int qa1  = ((4 + q) << 3) ^ fx8;    // kk=1
  const int rowA = (wm + fr) << 6;          // row * 64 elems
  const int rowB = (wn + fr) << 6;

  // staging: thread t covers rows j*64 + (t>>3); global col chunk pre-swizzled
  // by (row&7) so linear LDS dest yields swizzled layout (rule 21).
  const int srow = tid >> 3;                               // 0..63
  const int scol = ((tid & 7) ^ (srow & 7)) << 3;          // elems within BK=64
  const unsigned short* gA = A  + (size_t)(m0 + srow) * KDIM + scol;
  const unsigned short* gB = Bw + (size_t)(n0 + srow) * KDIM + scol;

  f32x4 acc[8][4] = {};

#define STAGE_A(kt, b)                                                          \
  {                                                                             \
    _Pragma("unroll")                                                           \
    for (int j = 0; j < 4; ++j)                                                 \
      __builtin_amdgcn_global_load_lds(                                         \
          (const __attribute__((address_space(1))) void*)(gA + (size_t)(kt) * 64 + (size_t)j * 64 * KDIM), \
          (__attribute__((address_space(3))) void*)(sA + (b) * 16384 + j * 4096 + tid * 8), 16, 0, 0); \
  }
#define STAGE_B(kt, b)                                                          \
  {                                                                             \
    _Pragma("unroll")                                                           \
    for (int j = 0; j < 4; ++j)                                                 \
      __builtin_amdgcn_global_load_lds(                                         \
          (const __attribute__((address_space(1))) void*)(gB + (size_t)(kt) * 64 + (size_t)j * 64 * KDIM), \
          (__attribute__((address_space(3))) void*)(sB + (b) * 16384 + j * 4096 + tid * 8), 16, 0, 0); \
  }

  // phase p computes acc rows 2p,2p+1 over K=64 (16 MFMA)
#define MFMA_PHASE(r0, r1, A0, A1, A2, A3)                                      \
  {                                                                             \
    _Pragma("unroll")                                                           \
    for (int j = 0; j < 4; ++j)                                                 \
      acc[r0][j] = __builtin_amdgcn_mfma_f32_16x16x32_bf16(A0, bf0[j], acc[r0][j], 0, 0, 0); \
    _Pragma("unroll")                                                           \
    for (int j = 0; j < 4; ++j)                                                 \
      acc[r1][j] = __builtin_amdgcn_mfma_f32_16x16x32_bf16(A2, bf0[j], acc[r1][j], 0, 0, 0); \
    _Pragma("unroll")                                                           \
    for (int j = 0; j < 4; ++j)                                                 \
      acc[r0][j] = __builtin_amdgcn_mfma_f32_16x16x32_bf16(A1, bf1[j], acc[r0][j], 0, 0, 0); \
    _Pragma("unroll")                                                           \
    for (int j = 0; j < 4; ++j)                                                 \
      acc[r1][j] = __builtin_amdgcn_mfma_f32_16x16x32_bf16(A3, bf1[j], acc[r1][j], 0, 0, 0); \
  }

#define READ_APAIR(d0, d1, d2, d3, buf, p)                                      \
  d0 = *(const bf16x8*)((buf) + rowA + (2 * (p)) * 1024 + qa0);                 \
  d1 = *(const bf16x8*)((buf) + rowA + (2 * (p)) * 1024 + qa1);                 \
  d2 = *(const bf16x8*)((buf) + rowA + (2 * (p) + 1) * 1024 + qa0);             \
  d3 = *(const bf16x8*)((buf) + rowA + (2 * (p) + 1) * 1024 + qa1);

  // prologue: stage tile 0 into buffer 0, wait, barrier, preload A-pair0
  STAGE_A(0, 0);
  STAGE_B(0, 0);
  asm volatile("s_waitcnt vmcnt(0)" ::: "memory");
  __builtin_amdgcn_s_barrier();

  bf16x8 aP0, aP1, aP2, aP3, aQ0, aQ1, aQ2, aQ3;
  bf16x8 bf0[4], bf1[4];
  READ_APAIR(aP0, aP1, aP2, aP3, sA, 0);

  for (int t = 0; t < NTILE; ++t) {
    const int cur = t & 1;
    const int nb  = cur ^ 1;
    const unsigned short* bufA  = sA + cur * 16384;
    const unsigned short* bufB  = sB + cur * 16384;
    const unsigned short* nbufA = sA + nb * 16384;
    const bool pf = (t + 1 < NTILE);

    // ---- S0: stage A(t+1); B frags + MFMA rows 0,1 ; read A-pair1 ----
    if (pf) STAGE_A(t + 1, nb);
#pragma unroll
    for (int j = 0; j < 4; ++j) {
      bf0[j] = *(const bf16x8*)(bufB + rowB + j * 1024 + qa0);
      bf1[j] = *(const bf16x8*)(bufB + rowB + j * 1024 + qa1);
    }
    __builtin_amdgcn_s_setprio(1);
    MFMA_PHASE(0, 1, aP0, aP1, aP2, aP3);
    __builtin_amdgcn_s_setprio(0);
    READ_APAIR(aQ0, aQ1, aQ2, aQ3, bufA, 1);
    __builtin_amdgcn_s_barrier();

    // ---- S1: stage B(t+1); MFMA rows 2,3 ; read A-pair2 ----
    if (pf) STAGE_B(t + 1, nb);
    __builtin_amdgcn_s_setprio(1);
    MFMA_PHASE(2, 3, aQ0, aQ1, aQ2, aQ3);
    __builtin_amdgcn_s_setprio(0);
    READ_APAIR(aP0, aP1, aP2, aP3, bufA, 2);
    __builtin_amdgcn_s_barrier();

    // ---- S2: MFMA rows 4,5 ; read A-pair3 ; vmcnt(0) ; barrier ----
    __builtin_amdgcn_s_setprio(1);
    MFMA_PHASE(4, 5, aP0, aP1, aP2, aP3);
    __builtin_amdgcn_s_setprio(0);
    READ_APAIR(aQ0, aQ1, aQ2, aQ3, bufA, 3);
    asm volatile("s_waitcnt vmcnt(0)" ::: "memory");
    __builtin_amdgcn_s_barrier();
    __builtin_amdgcn_sched_barrier(0);  // pin: no reads hoisted above this point

    // ---- S3: MFMA rows 6,7 ; read next tile's A-pair0 ----
    __builtin_amdgcn_s_setprio(1);
    MFMA_PHASE(6, 7, aQ0, aQ1, aQ2, aQ3);
    __builtin_amdgcn_s_setprio(0);
    if (pf) { READ_APAIR(aP0, aP1, aP2, aP3, nbufA, 0); }
    __builtin_amdgcn_s_barrier();
  }

  // epilogue: C/D layout col = lane&15, row = (lane>>4)*4 + reg
  const int r0 = m0 + wm + ((lane >> 4) << 2);
  const int c0 = n0 + wn + (lane & 15);
#pragma unroll
  for (int j = 0; j < 4; ++j) {
    const int col = c0 + j * 16;
    const float bb = bv[col];
#pragma unroll
    for (int i = 0; i < 8; ++i) {
      const int row = r0 + i * 16;
#pragma unroll
      for (int r = 0; r < 4; ++r)
        C[(size_t)(row + r) * NDIM + col] = acc[i][j][r] + bb;
    }
  }
#undef STAGE_A
#undef STAGE_B
#undef MFMA_PHASE
#undef READ_APAIR
}

extern "C" void kernel_launch(void* const* d_in, const int* in_sizes, int n_in,
                              void* d_out, int out_size, void* d_ws, size_t ws_size,
                              hipStream_t stream) {
  const float* x      = (const float*)d_in[0];
  const float* weight = (const float*)d_in[1];
  const float* bias   = (const float*)d_in[2];
  const float* scale  = (const float*)d_in[3];
  const int*   wq     = (const int*)d_in[4];
  const float* wscale = (const float*)d_in[5];
  const int*   wzp    = (const int*)d_in[6];
  const int*   bq     = (const int*)d_in[7];
  const float* bscale = (const float*)d_in[8];
  const int*   bzp    = (const int*)d_in[9];
  float* out = (float*)d_out;

  // workspace layout
  char* ws = (char*)d_ws;
  unsigned short* wd = (unsigned short*)(ws);                              // 32 MB  bf16 W'
  unsigned short* xb = (unsigned short*)(ws + 33554432);                   // 128 MB bf16 x
  float* bv = (float*)(ws + 33554432 + 134217728);                         // 16 KB  b'
  float* co = (float*)(ws + 33554432 + 134217728 + 16384);                 // coeffs

  coeff_kernel<<<1, 64, 0, stream>>>(scale, wscale, wzp, bscale, bzp, co);
  prep<<<8192 + 32768 + 16, 256, 0, stream>>>(weight, wq, co, wd, x, xb, bias, bq, bv);
  gemm256<<<dim3((MDIM / 256) * (NDIM / 256)), 512, 0, stream>>>(xb, wd, bv, out);
}